// Round 4
// baseline (164.185 us; speedup 1.0000x reference)
//
#include <hip/hip_runtime.h>

// NeuSSampler PDF importance resampling — segment-parallel, 2 rays/wave.
//
// Wave = 2 half-waves of 32 lanes; half h handles ray 2*wb+h. Lane owns 4
// weights/bins (m = lane&31, elements 4m..4m+3). Pair-sum scan via 5 DPP
// steps (row_shr:1/2/4/8 + row_bcast:15 rmask 0xa) = two independent
// 32-lane inclusive scans. One prologue serves two rays.
//
// Queries u_j=(2j+1)/130 are an arithmetic progression: segment k covers
// exactly j in [jf(cdf[k]), jf(cdf[k+1])), jf(c)=ceil(65c-0.5). Cross-lane
// shared edges are obtained by shuffle (bit-identical) so the per-lane
// ranges tile [0,65) exactly; clamping makes them nested-monotone under
// ulp-level cdf non-monotonicity. Last lane of each half forces j4=65 so
// query 64 is always claimed (rcp(0)=inf -> t clips to 1 -> bins[128],
// matching the reference's nan_to_num+clip gather).

#define DPP_FADD(x, ctrl, rmask)                                             \
    ((x) + __int_as_float(__builtin_amdgcn_update_dpp(                       \
               0, __float_as_int(x), (ctrl), (rmask), 0xf, true)))

__global__ __launch_bounds__(256) void neus_sampler_kernel(
    const float* __restrict__ weights,
    const float* __restrict__ bins_g,
    const float* __restrict__ nears,
    const float* __restrict__ fars,
    float* __restrict__ out,
    int R)
{
    constexpr int S  = 128;   // weights per ray
    constexpr int SE = 129;   // bin edges per ray
    constexpr int NB = 65;    // output samples per ray
    constexpr float HPAD = 1e-5f;

    const int lane = threadIdx.x & 63;
    const int m    = lane & 31;                 // element-quad index in half
    const int wb   = blockIdx.x * 4 + (threadIdx.x >> 6);
    const int rayA = wb * 2;
    if (rayA >= R) return;                      // wave-uniform exit
    const int ray  = rayA + (lane >> 5);
    const bool ok  = ray < R;                   // half-B validity (R odd tail)
    const int cray = ok ? ray : rayA;

    // ---- loads: weights as aligned float4 (row=512B), bins as 4 dwords ----
    const float4 wq =
        reinterpret_cast<const float4*>(weights + (size_t)cray * S)[m];
    const float* brow = bins_g + (size_t)cray * SE;
    const float bx = brow[4 * m];
    const float by = brow[4 * m + 1];
    const float bz = brow[4 * m + 2];
    const float bw = brow[4 * m + 3];
    const float b_last = brow[S];               // uniform per half
    const float nearv = nears[cray];
    const float farv  = fars[cray];

    const float w0 = wq.x + HPAD, w1 = wq.y + HPAD;
    const float w2 = wq.z + HPAD, w3 = wq.w + HPAD;
    const float p1 = w0, p2 = w0 + w1, p3 = p2 + w2, p4 = p3 + w3;

    // ---- two independent 32-lane inclusive scans of quad sums (DPP) ----
    float sc = p4;
    sc = DPP_FADD(sc, 0x111, 0xf);  // row_shr:1
    sc = DPP_FADD(sc, 0x112, 0xf);  // row_shr:2
    sc = DPP_FADD(sc, 0x114, 0xf);  // row_shr:4
    sc = DPP_FADD(sc, 0x118, 0xf);  // row_shr:8
    sc = DPP_FADD(sc, 0x142, 0xa);  // row_bcast:15 -> rows 1,3 only

    const float tA =
        __int_as_float(__builtin_amdgcn_readlane(__float_as_int(sc), 31));
    const float tB =
        __int_as_float(__builtin_amdgcn_readlane(__float_as_int(sc), 63));
    const float total   = (lane < 32) ? tA : tB;
    const float padding = fmaxf(1e-5f - total, 0.0f);   // relu(EPS - w_sum)
    const float padc    = padding * (1.0f / S);
    const float inv     = __builtin_amdgcn_rcpf(total + padding);
    const float excl    = sc - p4;              // exclusive scan (raw cumsum)

    // ---- per-lane cdf edges e1..e4 (edge index 4m+k) ----
    const float mb = (float)(4 * m);
    const float e1 = fminf(1.0f, fmaf(mb + 1.0f, padc, excl + p1) * inv);
    const float e2 = fminf(1.0f, fmaf(mb + 2.0f, padc, excl + p2) * inv);
    const float e3 = fminf(1.0f, fmaf(mb + 3.0f, padc, excl + p3) * inv);
    const float e4 = fminf(1.0f, fmaf(mb + 4.0f, padc, excl + p4) * inv);

    float e0 = __shfl_up(e4, 1, 64);            // cdf[4m] from prev lane
    if (m == 0) e0 = 0.0f;                      // cdf[0] per half
    float b4 = __shfl_down(bx, 1, 64);          // bins[4m+4]
    if (m == 31) b4 = b_last;                   // bins[128] per half

    // first query index j with u_j >= c  (u_j = (2j+1)/130)
    auto jf = [](float c) -> int {
        int j = (int)ceilf(fmaf(65.0f, c, -0.5f));
        return j < 0 ? 0 : (j > NB ? NB : j);
    };

    int j0 = jf(e0);                            // bit-identical to prev j4
    int j4 = (m == 31) ? NB : jf(e4);
    if (!ok) { j0 = 0; j4 = 0; }                // invalid half: empty ranges
    j4 = j4 < j0 ? j0 : j4;
    int j1 = jf(e1); j1 = j1 < j0 ? j0 : (j1 > j4 ? j4 : j1);
    int j2 = jf(e2); j2 = j2 < j1 ? j1 : (j2 > j4 ? j4 : j2);
    int j3 = jf(e3); j3 = j3 < j2 ? j2 : (j3 > j4 ? j4 : j3);

    const float fmn = farv - nearv;
    float* orow = out + (size_t)cray * NB;

    auto seg = [&](float clo, float chi, float b0, float b1, int js, int je) {
        if (je > js) {
            const float r  = __builtin_amdgcn_rcpf(chi - clo);  // inf if d==0
            const float dt = r * (1.0f / 65.0f);
            const float bd = b1 - b0;
            float t = (fmaf((float)(2 * js + 1), (1.0f / 130.0f), -clo)) * r;
            for (int j = js; j < je; ++j) {
                const float tc = fminf(fmaxf(t, 0.0f), 1.0f);  // NaN-safe ->0
                orow[j] = fmaf(fmaf(tc, bd, b0), fmn, nearv);
                t += dt;
            }
        }
    };

    seg(e0, e1, bx, by, j0, j1);
    seg(e1, e2, by, bz, j1, j2);
    seg(e2, e3, bz, bw, j2, j3);
    seg(e3, e4, bw, b4, j3, j4);
}

extern "C" void kernel_launch(void* const* d_in, const int* in_sizes, int n_in,
                              void* d_out, int out_size, void* d_ws, size_t ws_size,
                              hipStream_t stream) {
    const float* weights = (const float*)d_in[0];   // [R,128,1]
    const float* ebins   = (const float*)d_in[1];   // [R,129]
    const float* nears   = (const float*)d_in[2];   // [R,1]
    const float* fars    = (const float*)d_in[3];   // [R,1]
    float* out = (float*)d_out;                     // [R,65]
    const int R = in_sizes[0] / 128;
    const int blocks = (R + 7) / 8;                 // 8 rays per 256-thr block
    hipLaunchKernelGGL(neus_sampler_kernel, dim3(blocks), dim3(256), 0, stream,
                       weights, ebins, nears, fars, out, R);
}